// Round 6
// baseline (250.471 us; speedup 1.0000x reference)
//
#include <hip/hip_runtime.h>

// kernel:  (N=8, K2=25, H=128, W=128) fp32
// low_fea: (N=8, C=256, H=128, W=128) fp32
// out[n,c,y,x] = low_fea[n,c,y,x] * S[n,y,x]
// S[n,y,x]  = sum_{a,b in [0,5)} kernel[n, a*5+b, y+2-a, x+2-b]  (0 outside bounds)
//
// Fused, one dispatch. Block = (n, row-pair, channel-quarter). 2048 blocks:
//   phase 1: ALL 256 threads each compute a FULL sequential 25-tap sum
//            (thread = (row-half r, x); rows y0, y0+1). Tap order is identical
//            to the JAX reference (a-major, b-minor, skip = add 0) -> bit-exact
//            (round-3's tap-split reassociated the sum -> absmax 0.125; this
//            restores absmax 0.0 while keeping all threads busy in phase 1).
//   phase 2: stream 2 rows x 64 channels: out = low * S, float4 NT.
//
// XCD pinning: dispatcher round-robins blockIdx.x over 8 XCDs (b & 7); n = b & 7
// keeps kernel[n] (1.64 MB) resident in one XCD's 4 MiB L2, so the 5x vertical
// tap overlap and the 4x chunk recompute are L2 hits, not HBM re-fetch.
// HBM traffic: 134 MB low + ~13 MB kernel reads, 134 MB writes -> ~45 us @ 6.3 TB/s.
#define NN 8
#define CC 256
#define HH 128
#define WW 128
#define KK 5
#define PAD 2

typedef float f4 __attribute__((ext_vector_type(4)));

__global__ __launch_bounds__(256) void fused_kernel(
    const float* __restrict__ kern,
    const float* __restrict__ low,
    float* __restrict__ out)
{
    __shared__ __align__(16) float S[2][WW];

    const int b     = blockIdx.x;
    const int n     = b & (NN - 1);          // XCD-pinned batch index
    const int rest  = b >> 3;                // 0..255
    const int ypair = rest & 63;             // 0..63
    const int chunk = rest >> 6;             // 0..3 (channel quarter)
    const int y0    = ypair << 1;
    const int tid   = threadIdx.x;

    // ---- phase 1: full sequential S for rows y0, y0+1; all 256 threads ----
    {
        const int r = tid >> 7;              // which row of the pair
        const int x = tid & (WW - 1);
        const int y = y0 + r;
        float s = 0.0f;
        const float* kb = kern + (size_t)n * (KK * KK * HH * WW);
#pragma unroll
        for (int a = 0; a < KK; ++a) {
            const int yy = y + PAD - a;
            if (yy >= 0 && yy < HH) {
#pragma unroll
                for (int bb = 0; bb < KK; ++bb) {
                    const int xx = x + PAD - bb;
                    if (xx >= 0 && xx < WW) {
                        s += kb[((a * KK + bb) * HH + yy) * WW + xx];
                    }
                }
            }
        }
        S[r][x] = s;
    }
    __syncthreads();

    // ---- phase 2: stream 2 rows x 64 channels of (n, y0..y0+1) ----
    const int xq = tid & 31;                 // float4 index in row (W/4 = 32)
    const int c0 = (chunk << 6) + (tid >> 5);

    const f4* __restrict__ lf4 = (const f4*)(low + (size_t)n * (CC * HH * WW));
    f4* __restrict__       o4  = (f4*)      (out + (size_t)n * (CC * HH * WW));

#pragma unroll
    for (int r = 0; r < 2; ++r) {
        const f4 s4 = *(const f4*)&S[r][xq * 4];
        const size_t rowbase = (size_t)(y0 + r) * (WW / 4) + xq;
#pragma unroll
        for (int it = 0; it < 8; ++it) {
            const int    c   = c0 + it * 8;
            const size_t idx = (size_t)c * (HH * WW / 4) + rowbase;
            f4 v = __builtin_nontemporal_load(lf4 + idx);    // zero-reuse stream
            __builtin_nontemporal_store(v * s4, o4 + idx);   // write-only stream
        }
    }
}

extern "C" void kernel_launch(void* const* d_in, const int* in_sizes, int n_in,
                              void* d_out, int out_size, void* d_ws, size_t ws_size,
                              hipStream_t stream) {
    const float* kern = (const float*)d_in[0];  // (8, 25, 128, 128)
    const float* low  = (const float*)d_in[1];  // (8, 256, 128, 128)
    float* out = (float*)d_out;                 // (8, 256, 128, 128)
    (void)d_ws; (void)ws_size;

    fused_kernel<<<dim3(NN * (HH / 2) * 4), dim3(256), 0, stream>>>(kern, low, out);
}